// Round 6
// baseline (1852.267 us; speedup 1.0000x reference)
//
#include <hip/hip_runtime.h>
#include <math.h>

// DeepHeadClassifier — round 7: wave-private pipeline, ZERO barriers.
// Evidence r0/r5/r6: occupancy pinned at ~8 waves/CU regardless of LDS
// (54K/53K/41K all -> 2 blocks); all pipes <25% busy; wall = ~20 lockstep
// barrier phases x ~8.6K cycles. Fix: each wave owns 4 batch rows end-to-end
// with private LDS slices; no __syncthreads anywhere -> 8 resident waves/CU
// slide independently, overlapping MFMA/VALU/LDS/VMEM phases (m114).
// MFMA m-tiles: 12 valid token rows + zeroed pad rows (junk finite, ignored).
// r6's acc3-across-phases spill avoided by keeping per-phase acc scopes tight.

#define E   256
#define NC  7
#define BM  16      // batch rows per block (4 waves x 4 rows)
#define NT  256
#define BSX 264     // s_x row stride (elems): 528 B, 16B-aligned, 2-way bank alias
#define BSB 136     // s_buf row stride (elems): 272 B, 2-way bank alias

typedef unsigned short u16;
typedef unsigned int   u32;
typedef __attribute__((ext_vector_type(8))) short  short8;
typedef __attribute__((ext_vector_type(4))) float  f32x4;

// ws layout (bf16 elements)
#define O_IPW 0
#define O_OW  196608
#define O_GW  262144
#define O_W1  264448
#define O_W2  329984
#define CVT_TOTAL 362752

__device__ __forceinline__ float bf2f(u32 u) { return __uint_as_float(u << 16); }
__device__ __forceinline__ u16 f2bf(float f) {
    u32 u = __float_as_uint(f);
    return (u16)((u + 0x7fffu + ((u >> 16) & 1u)) >> 16);
}

__global__ void cvt_weights(const float* __restrict__ ipw, const float* __restrict__ ow,
                            const float* __restrict__ gw,  const float* __restrict__ w1,
                            const float* __restrict__ w2,  u16* __restrict__ ws) {
    int i4 = (blockIdx.x * 256 + threadIdx.x) * 4;
    if (i4 >= CVT_TOTAL) return;
    const float* src; int off;
    if      (i4 < O_OW)  { src = ipw; off = i4; }
    else if (i4 < O_GW)  { src = ow;  off = i4 - O_OW; }
    else if (i4 < O_W1)  { src = gw;  off = i4 - O_GW; }
    else if (i4 < O_W2)  { src = w1;  off = i4 - O_W1; }
    else                 { src = w2;  off = i4 - O_W2; }
    float4 v = *(const float4*)(src + off);
    ushort4 o;
    o.x = f2bf(v.x); o.y = f2bf(v.y); o.z = f2bf(v.z); o.w = f2bf(v.w);
    *(ushort4*)(ws + i4) = o;
}

// Per-wave MFMA GEMM: one 16-row m-tile. A from this wave's LDS slice
// (row = l16, stride aStride), B rows from global ws ([N][256] bf16).
template<int NTW, int KSN, bool ZERO>
__device__ __forceinline__ void gemm1(const u16* aBase, int aStride, 
                                      const u16* __restrict__ bW, int rowBase, int bCol0,
                                      int lane, f32x4 (&acc)[NTW]) {
    const int l16 = lane & 15, quad = lane >> 4;
    if (ZERO) {
        #pragma unroll
        for (int j = 0; j < NTW; ++j) acc[j] = (f32x4){0.f, 0.f, 0.f, 0.f};
    }
    #pragma unroll
    for (int ks = 0; ks < KSN; ++ks) {
        short8 a = *(const short8*)(aBase + (size_t)l16 * aStride + ks * 32 + quad * 8);
        #pragma unroll
        for (int j = 0; j < NTW; ++j) {
            short8 b = *(const short8*)(bW + (size_t)(rowBase + j * 16 + l16) * 256 + bCol0 + ks * 32 + quad * 8);
            acc[j] = __builtin_amdgcn_mfma_f32_16x16x32_bf16(a, b, acc[j], 0, 0, 0);
        }
    }
}

__global__ __launch_bounds__(NT, 2)
void dhc_mfma_kernel(
    const float* __restrict__ f0, const float* __restrict__ f1, const float* __restrict__ f2,
    const float* __restrict__ ipb, const float* __restrict__ ob,
    const float* __restrict__ ln1g, const float* __restrict__ ln1b,
    const float* __restrict__ gb,
    const float* __restrict__ ln2g, const float* __restrict__ ln2b,
    const float* __restrict__ b1, const float* __restrict__ b2,
    const float* __restrict__ w3, const float* __restrict__ b3,
    const u16* __restrict__ ws, float* __restrict__ d_out, int nrows)
{
    // Per-wave private slices (wave w owns rows [16w,16w+16) of each array).
    __shared__ __align__(16) u16 s_x[64 * BSX];     // 33792 B
    __shared__ __align__(16) u16 s_buf[64 * BSB];   // 17408 B
    __shared__ __align__(16) float s_small[4 * 192]; // 3072 B  (total 54272)
    // sm layout per wave: [0..143] attn[r][h][9]; [144..155] gate wgt[r][3];
    // [156..167] mu1[12]; [168..179] rstd1[12]; [180..183] mu2[4]; [184..187] rstd2[4]

    const int tid  = threadIdx.x;
    const int wid  = tid >> 6, lane = tid & 63;
    const int l16  = lane & 15, quad = lane >> 4;
    const long long row0 = (long long)blockIdx.x * BM + wid * 4;   // wave's first batch row
    const size_t fused_base = (size_t)nrows * NC;

    u16*   sx = s_x   + wid * 16 * BSX;
    u16*   sb = s_buf + wid * 16 * BSB;
    float* sm = s_small + wid * 192;

    const u16* ipw_b = ws + O_IPW;
    const u16* ow_b  = ws + O_OW;
    const u16* gw_b  = ws + O_GW;
    const u16* w1_b  = ws + O_W1;
    const u16* w2_b  = ws + O_W2;

    // ---- P0: this wave's 12 token rows fp32 -> bf16; zero pad rows 12..15 ----
    #pragma unroll
    for (int t = 0; t < 12; ++t) {
        int s = t >> 2, r = t & 3;
        float4 v = {0.f, 0.f, 0.f, 0.f};
        if (row0 + r < nrows) {
            const float* src = (s == 0 ? f0 : (s == 1 ? f1 : f2));
            v = *(const float4*)(src + (size_t)(row0 + r) * E + lane * 4);
        }
        ushort4 o;
        o.x = f2bf(v.x); o.y = f2bf(v.y); o.z = f2bf(v.z); o.w = f2bf(v.w);
        *(ushort4*)(sx + t * BSX + lane * 4) = o;
    }
    {
        ushort4 z = {0, 0, 0, 0};
        #pragma unroll
        for (int t = 12; t < 16; ++t) *(ushort4*)(sx + t * BSX + lane * 4) = z;
    }

    // ---- Gate (36 lanes: r,g,s), shuffle-combined; reads ORIGINAL x ----
    if (lane < 36) {
        int r = lane / 9, rem = lane % 9, g = rem / 3, s = rem % 3;
        const u16* xp = sx + (s * 4 + r) * BSX;
        const u16* wp = gw_b + g * 768 + s * 256;
        float a0 = 0.f, a1 = 0.f, a2 = 0.f, a3 = 0.f;
        #pragma unroll
        for (int c8 = 0; c8 < 8; ++c8) {
            #pragma unroll
            for (int q4 = 0; q4 < 4; ++q4) {
                short8 xv = *(const short8*)(xp + (c8 * 4 + q4) * 8);
                short8 wv = *(const short8*)(wp + (c8 * 4 + q4) * 8);
                float t = 0.f;
                #pragma unroll
                for (int e = 0; e < 8; ++e)
                    t += bf2f((u32)(u16)xv[e]) * bf2f((u32)(u16)wv[e]);
                if      (q4 == 0) a0 += t;
                else if (q4 == 1) a1 += t;
                else if (q4 == 2) a2 += t;
                else              a3 += t;
            }
        }
        float part = (a0 + a1) + (a2 + a3);
        int base = r * 9 + g * 3;
        float tot = __shfl(part, base) + __shfl(part, base + 1) + __shfl(part, base + 2);
        float logit = tot + gb[g];
        int br = r * 9;
        float l0 = __shfl(logit, br + 0);
        float l1 = __shfl(logit, br + 3);
        float l2 = __shfl(logit, br + 6);
        float mx = fmaxf(l0, fmaxf(l1, l2));
        float e0 = __expf(l0 - mx), e1 = __expf(l1 - mx), e2 = __expf(l2 - mx);
        float w = __expf(logit - mx) / (e0 + e1 + e2);
        if (s == 0) sm[144 + r * 3 + g] = w;
    }

    // ---- qk: 4 per-head passes, in-wave softmax ----
    for (int h = 0; h < 4; ++h) {
        f32x4 aq[4], ak[4];
        gemm1<4, 8, true>(sx, BSX, ipw_b, 64 * h, 0, lane, aq);
        gemm1<4, 8, true>(sx, BSX, ipw_b, 256 + 64 * h, 0, lane, ak);
        #pragma unroll
        for (int j = 0; j < 4; ++j) {
            float bq_ = ipb[64 * h + j * 16 + l16];
            float bk_ = ipb[256 + 64 * h + j * 16 + l16];
            #pragma unroll
            for (int rr = 0; rr < 4; ++rr) {
                int tok = quad * 4 + rr;
                sb[tok * BSB + j * 16 + l16]      = f2bf(aq[j][rr] + bq_);
                sb[tok * BSB + 64 + j * 16 + l16] = f2bf(ak[j][rr] + bk_);
            }
        }
        if (lane < 12) {
            int r = lane / 3, i = lane % 3;
            const u16* qrow = sb + (i * 4 + r) * BSB;
            const u16* k0 = sb + (0 + r) * BSB + 64;
            const u16* k1 = sb + (4 + r) * BSB + 64;
            const u16* k2 = sb + (8 + r) * BSB + 64;
            float d0a = 0.f, d0b = 0.f, d1a = 0.f, d1b = 0.f, d2a = 0.f, d2b = 0.f;
            #pragma unroll
            for (int d8 = 0; d8 < 8; ++d8) {
                short8 qv = *(const short8*)(qrow + d8 * 8);
                short8 a0 = *(const short8*)(k0 + d8 * 8);
                short8 a1 = *(const short8*)(k1 + d8 * 8);
                short8 a2 = *(const short8*)(k2 + d8 * 8);
                #pragma unroll
                for (int e = 0; e < 4; ++e) {
                    float qa = bf2f((u32)(u16)qv[e]);
                    float qb = bf2f((u32)(u16)qv[e + 4]);
                    d0a += qa * bf2f((u32)(u16)a0[e]); d0b += qb * bf2f((u32)(u16)a0[e + 4]);
                    d1a += qa * bf2f((u32)(u16)a1[e]); d1b += qb * bf2f((u32)(u16)a1[e + 4]);
                    d2a += qa * bf2f((u32)(u16)a2[e]); d2b += qb * bf2f((u32)(u16)a2[e + 4]);
                }
            }
            float d0 = (d0a + d0b) * 0.125f, d1 = (d1a + d1b) * 0.125f, d2 = (d2a + d2b) * 0.125f;
            float mx = fmaxf(d0, fmaxf(d1, d2));
            float e0 = __expf(d0 - mx), e1 = __expf(d1 - mx), e2 = __expf(d2 - mx);
            float inv = 1.f / (e0 + e1 + e2);
            float* ap = sm + (r * 4 + h) * 9 + i * 3;
            ap[0] = e0 * inv; ap[1] = e1 * inv; ap[2] = e2 * inv;
        }
    }

    // ---- v / ctx / out_proj in two 128-col halves; out_proj K-accumulated ----
    {
        f32x4 a3[16];
        #pragma unroll
        for (int j = 0; j < 16; ++j) a3[j] = (f32x4){0.f, 0.f, 0.f, 0.f};
        for (int hv = 0; hv < 2; ++hv) {
            f32x4 av[8];
            gemm1<8, 8, true>(sx, BSX, ipw_b, 512 + 128 * hv, 0, lane, av);
            #pragma unroll
            for (int j = 0; j < 8; ++j) {
                float bias = ipb[512 + 128 * hv + j * 16 + l16];
                #pragma unroll
                for (int rr = 0; rr < 4; ++rr) {
                    int tok = quad * 4 + rr;
                    sb[tok * BSB + j * 16 + l16] = f2bf(av[j][rr] + bias);
                }
            }
            // ctx = attn (x) v, in place (lane = (r, 8-col group))
            {
                int r = lane >> 4, cg = lane & 15;
                int h = 2 * hv + (cg >> 3);
                float a[9];
                #pragma unroll
                for (int q2 = 0; q2 < 9; ++q2) a[q2] = sm[(r * 4 + h) * 9 + q2];
                #pragma unroll
                for (int cc = 0; cc < 8; ++cc) {
                    int c = cg * 8 + cc;
                    float v0 = bf2f((u32)sb[(0 + r) * BSB + c]);
                    float v1 = bf2f((u32)sb[(4 + r) * BSB + c]);
                    float v2 = bf2f((u32)sb[(8 + r) * BSB + c]);
                    float c0 = a[0] * v0 + a[1] * v1 + a[2] * v2;
                    float c1 = a[3] * v0 + a[4] * v1 + a[5] * v2;
                    float c2 = a[6] * v0 + a[7] * v1 + a[8] * v2;
                    sb[(0 + r) * BSB + c] = f2bf(c0);
                    sb[(4 + r) * BSB + c] = f2bf(c1);
                    sb[(8 + r) * BSB + c] = f2bf(c2);
                }
            }
            gemm1<16, 4, false>(sb, BSB, ow_b, 0, 128 * hv, lane, a3);
        }
        // out_proj epilogue: + ob + residual -> x_res in place in s_x
        #pragma unroll
        for (int j = 0; j < 16; ++j) {
            int n = j * 16 + l16;
            float bias = ob[n];
            #pragma unroll
            for (int rr = 0; rr < 4; ++rr) {
                int tok = quad * 4 + rr;
                float vv = a3[j][rr] + bias + bf2f((u32)sx[tok * BSX + n]);
                sx[tok * BSX + n] = f2bf(vv);
            }
        }
    }

    // ---- LN1 stats (48 lanes: 12 rows x 4) ----
    if (lane < 48) {
        int r12 = lane >> 2, jj = lane & 3;
        const u16* xp = sx + r12 * BSX + jj * 64;
        float s0 = 0.f, s1 = 0.f, q0 = 0.f, q1 = 0.f;
        #pragma unroll
        for (int c8 = 0; c8 < 8; ++c8) {
            short8 v = *(const short8*)(xp + c8 * 8);
            #pragma unroll
            for (int e = 0; e < 4; ++e) {
                float xa = bf2f((u32)(u16)v[e]);
                float xb = bf2f((u32)(u16)v[e + 4]);
                s0 += xa; q0 += xa * xa;
                s1 += xb; q1 += xb * xb;
            }
        }
        float sum = s0 + s1, sq = q0 + q1;
        sum += __shfl_xor(sum, 1); sq += __shfl_xor(sq, 1);
        sum += __shfl_xor(sum, 2); sq += __shfl_xor(sq, 2);
        if (jj == 0) {
            float mu = sum * (1.f / 256.f);
            float var = sq * (1.f / 256.f) - mu * mu;
            sm[156 + r12] = mu;
            sm[168 + r12] = rsqrtf(var + 1e-5f);
        }
    }
    // ---- LN1 apply (lane = 4 cols, 12 rows) ----
    {
        int c = lane * 4;
        float4 gv = *(const float4*)(ln1g + c);
        float4 bv = *(const float4*)(ln1b + c);
        #pragma unroll
        for (int t = 0; t < 12; ++t) {
            float mu = sm[156 + t], rs = sm[168 + t];
            ushort4 xv = *(ushort4*)(sx + t * BSX + c);
            ushort4 o;
            o.x = f2bf((bf2f(xv.x) - mu) * rs * gv.x + bv.x);
            o.y = f2bf((bf2f(xv.y) - mu) * rs * gv.y + bv.y);
            o.z = f2bf((bf2f(xv.z) - mu) * rs * gv.z + bv.z);
            o.w = f2bf((bf2f(xv.w) - mu) * rs * gv.w + bv.w);
            *(ushort4*)(sx + t * BSX + c) = o;
        }
    }

    // ---- fused -> global fp32; h0 bf16 into s_x rows 0..3 ----
    {
        int c = lane * 4;
        #pragma unroll
        for (int r = 0; r < 4; ++r) {
            float w0 = sm[144 + r * 3 + 0];
            float w1v = sm[144 + r * 3 + 1];
            float w2v = sm[144 + r * 3 + 2];
            ushort4 x0 = *(ushort4*)(sx + (0 + r) * BSX + c);
            ushort4 x1 = *(ushort4*)(sx + (4 + r) * BSX + c);
            ushort4 x2 = *(ushort4*)(sx + (8 + r) * BSX + c);
            float4 f;
            f.x = w0 * bf2f(x0.x) + w1v * bf2f(x1.x) + w2v * bf2f(x2.x);
            f.y = w0 * bf2f(x0.y) + w1v * bf2f(x1.y) + w2v * bf2f(x2.y);
            f.z = w0 * bf2f(x0.z) + w1v * bf2f(x1.z) + w2v * bf2f(x2.z);
            f.w = w0 * bf2f(x0.w) + w1v * bf2f(x1.w) + w2v * bf2f(x2.w);
            if (row0 + r < nrows)
                *(float4*)(d_out + fused_base + (size_t)(row0 + r) * E + c) = f;
            ushort4 o;
            o.x = f2bf(f.x); o.y = f2bf(f.y); o.z = f2bf(f.z); o.w = f2bf(f.w);
            *(ushort4*)(sx + r * BSX + c) = o;
        }
    }

    // ---- LN2 stats (64 lanes: 4 rows x 16) ----
    {
        int r = lane >> 4, jj = lane & 15;
        const u16* fp = sx + r * BSX + jj * 16;
        float sum = 0.f, sq = 0.f;
        #pragma unroll
        for (int c8 = 0; c8 < 2; ++c8) {
            short8 v = *(const short8*)(fp + c8 * 8);
            #pragma unroll
            for (int e = 0; e < 8; ++e) {
                float x = bf2f((u32)(u16)v[e]);
                sum += x; sq += x * x;
            }
        }
        sum += __shfl_xor(sum, 1); sq += __shfl_xor(sq, 1);
        sum += __shfl_xor(sum, 2); sq += __shfl_xor(sq, 2);
        sum += __shfl_xor(sum, 4); sq += __shfl_xor(sq, 4);
        sum += __shfl_xor(sum, 8); sq += __shfl_xor(sq, 8);
        if (jj == 0) {
            float mu = sum * (1.f / 256.f);
            float var = sq * (1.f / 256.f) - mu * mu;
            sm[180 + r] = mu;
            sm[184 + r] = rsqrtf(var + 1e-5f);
        }
    }
    // ---- LN2 apply (lane = 4 cols, 4 rows) ----
    {
        int c = lane * 4;
        float4 gv = *(const float4*)(ln2g + c);
        float4 bv = *(const float4*)(ln2b + c);
        #pragma unroll
        for (int r = 0; r < 4; ++r) {
            float mu = sm[180 + r], rs = sm[184 + r];
            ushort4 xv = *(ushort4*)(sx + r * BSX + c);
            ushort4 o;
            o.x = f2bf((bf2f(xv.x) - mu) * rs * gv.x + bv.x);
            o.y = f2bf((bf2f(xv.y) - mu) * rs * gv.y + bv.y);
            o.z = f2bf((bf2f(xv.z) - mu) * rs * gv.z + bv.z);
            o.w = f2bf((bf2f(xv.w) - mu) * rs * gv.w + bv.w);
            *(ushort4*)(sx + r * BSX + c) = o;
        }
    }

    // ---- G4: h1 = gelu(h0 @ w1^T + b1) -> s_x rows (all 16; 0..3 valid) ----
    {
        f32x4 a4[16];
        gemm1<16, 8, true>(sx, BSX, w1_b, 0, 0, lane, a4);
        #pragma unroll
        for (int j = 0; j < 16; ++j) {
            int n = j * 16 + l16;
            float bias = b1[n];
            #pragma unroll
            for (int rr = 0; rr < 4; ++rr) {
                int tok = quad * 4 + rr;
                float x = a4[j][rr] + bias;
                float hg = 0.5f * x * (1.f + erff(x * 0.70710678118654752f));
                sx[tok * BSX + n] = f2bf(hg);
            }
        }
    }

    // ---- G5: h2 = gelu(h1 @ w2^T + b2) -> s_buf cols 0..127 ----
    {
        f32x4 a5[8];
        gemm1<8, 8, true>(sx, BSX, w2_b, 0, 0, lane, a5);
        #pragma unroll
        for (int j = 0; j < 8; ++j) {
            int n = j * 16 + l16;
            float bias = b2[n];
            #pragma unroll
            for (int rr = 0; rr < 4; ++rr) {
                int tok = quad * 4 + rr;
                float x = a5[j][rr] + bias;
                float hg = 0.5f * x * (1.f + erff(x * 0.70710678118654752f));
                sb[tok * BSB + n] = f2bf(hg);
            }
        }
    }

    // ---- logits (28 lanes: 4 rows x 7 classes) ----
    if (lane < 28) {
        int r = lane / 7, n = lane % 7;
        const float* wr = w3 + n * 128;
        const u16* hp = sb + r * BSB;
        float a0 = 0.f, a1 = 0.f, a2 = 0.f, a3 = 0.f;
        #pragma unroll
        for (int q8 = 0; q8 < 8; ++q8) {
            #pragma unroll
            for (int q4 = 0; q4 < 4; ++q4) {
                int k4 = q8 * 4 + q4;
                float4 w = *(const float4*)(wr + k4 * 4);
                float t = bf2f((u32)hp[k4 * 4 + 0]) * w.x
                        + bf2f((u32)hp[k4 * 4 + 1]) * w.y
                        + bf2f((u32)hp[k4 * 4 + 2]) * w.z
                        + bf2f((u32)hp[k4 * 4 + 3]) * w.w;
                if      (q4 == 0) a0 += t;
                else if (q4 == 1) a1 += t;
                else if (q4 == 2) a2 += t;
                else              a3 += t;
            }
        }
        float acc = b3[n] + (a0 + a1) + (a2 + a3);
        if (row0 + r < nrows) d_out[(size_t)(row0 + r) * NC + n] = acc;
    }
}

extern "C" void kernel_launch(void* const* d_in, const int* in_sizes, int n_in,
                              void* d_out, int out_size, void* d_ws, size_t ws_size,
                              hipStream_t stream) {
    (void)n_in; (void)ws_size; (void)out_size;
    const int nrows = in_sizes[0] / E;
    u16* ws = (u16*)d_ws;
    cvt_weights<<<(CVT_TOTAL / 4 + 255) / 256, 256, 0, stream>>>(
        (const float*)d_in[3], (const float*)d_in[5], (const float*)d_in[9],
        (const float*)d_in[13], (const float*)d_in[15], ws);
    const int nblocks = (nrows + BM - 1) / BM;
    dhc_mfma_kernel<<<nblocks, NT, 0, stream>>>(
        (const float*)d_in[0], (const float*)d_in[1], (const float*)d_in[2],
        (const float*)d_in[4], (const float*)d_in[6],
        (const float*)d_in[7], (const float*)d_in[8],
        (const float*)d_in[10],
        (const float*)d_in[11], (const float*)d_in[12],
        (const float*)d_in[14], (const float*)d_in[16],
        (const float*)d_in[17], (const float*)d_in[18],
        ws, (float*)d_out, nrows);
}